// Round 13
// baseline (72.149 us; speedup 1.0000x reference)
//
#include <hip/hip_runtime.h>

#define HH 1024
#define WW 1024
#define KK 9
#define PADK 4
#define TSX 16
#define TSY 8
#define TROWS 16     // TSY + 2*PADK
#define TCOLS 24     // TSX + 2*PADK
#define TSTR 26      // float4 row stride (pad 24->26: quadrant reads hit 4 distinct bank-groups)
#define NW 81
#define CHF 2592     // chunk floats = 32 px * 81
#define HALF 1296    // per-wave half chunk (16 px, 5184 B contiguous)

#define GLDS(src, dst, w)                                              \
  __builtin_amdgcn_global_load_lds(                                    \
      (const __attribute__((address_space(1))) unsigned int*)(src),    \
      (__attribute__((address_space(3))) unsigned int*)(dst), w, 0, 0)

#define SBAR __builtin_amdgcn_sched_barrier(0)

// Single-pass + pipelined KPN. Block = 128 thr = 16x8 px. Weights arrive in
// 4 x 10368 B PIXEL-contiguous chunks (32 px full weights each; 128B-aligned
// -> each cnn byte fetched exactly once) double-buffered in 20.7 KB LDS.
// Per phase all 128 threads compute 32 px (4 thr/px, k-split 20/20/20/21,
// shfl_xor reduce). Each wave stages exactly the chunk-half its lanes read
// -> no weight barriers; per-wave counted vmcnt(6/7/7/1) keeps the next
// chunk in flight across every compute phase (never idle HBM queue, R12's
// measured ~1150 cyc/job exposed tail). 27.4 KB LDS -> 5 blocks/CU.
__global__ __launch_bounds__(128) void denoiser_kpn(
    const float* __restrict__ unet, const float* __restrict__ cnn,
    float* __restrict__ out) {
  __shared__ float4 tile[TROWS][TSTR];  // 6656 B
  __shared__ float wlds[2][CHF];        // 20736 B

  const int tid = threadIdx.x;
  const int lane = tid & 63;
  const int wv = tid >> 6;    // wave 0/1
  const int q = tid >> 2;     // chunk-pixel 0..31 (wave0: 0..15, wave1: 16..31)
  const int jj = tid & 3;     // k-split lane: taps [20*jj, 20*jj+20(+1 if jj==3))
  const int tx = q & 15;
  const int px0 = blockIdx.x * TSX;
  const int py0 = blockIdx.y * TSY;

  // Chunk c = block rows {2c, 2c+1}; wave wv stages row 2c+wv (its own half:
  // 5184 contiguous bytes = 5x1024 + 64B tail) -> 6 VMEM ops per wave.
  auto wdma = [&](int c, int buf) {
    const char* s =
        (const char*)(cnn + ((size_t)((py0 + 2 * c + wv) * WW + px0)) * NW);
    char* d = (char*)&wlds[buf][wv * HALF];
#pragma unroll
    for (int i = 0; i < 5; ++i)
      GLDS(s + i * 1024 + lane * 16, d + i * 1024 + lane * 16, 16);
    if (lane < 4) GLDS(s + 5120 + lane * 16, d + 5120 + lane * 16, 16);
  };

  // Phase: 32 px, 4 thr/px. Walk k = 20*jj + n with incremental (kj, tidx).
  auto do_phase = [&](const float* wb, int trow, int gy) {
    float ax = 0.f, ay = 0.f, az = 0.f;
    int kj = 2 * jj;                              // k0 = 20*jj -> (ki,kj)=(2jj,2jj)
    int tidx = (trow + 2 * jj) * TSTR + tx + kj;  // float4 index
#pragma unroll
    for (int n = 0; n < 21; ++n) {
      if (n < 20 || jj == 3) {
        const float4 pv = ((const float4*)tile)[tidx];
        const float w = wb[n];
        ax = fmaf(w, pv.x, ax);
        ay = fmaf(w, pv.y, ay);
        az = fmaf(w, pv.z, az);
      }
      ++kj;
      ++tidx;
      const bool wrap = (kj == KK);
      kj = wrap ? 0 : kj;
      tidx += wrap ? (TSTR - KK) : 0;
    }
    ax += __shfl_xor(ax, 1); ax += __shfl_xor(ax, 2);
    ay += __shfl_xor(ay, 1); ay += __shfl_xor(ay, 2);
    az += __shfl_xor(az, 1); az += __shfl_xor(az, 2);
    if (jj == 0) {
      const float o[3] = {ax, ay, az};
      __builtin_memcpy(out + ((size_t)gy * WW + px0 + tx) * 3, &o[0], 12);
    }
  };

  // ---- Prologue: tile gloads (oldest VMEM), then C0,C1 DMA. ----
  float tr_[3][3];
#pragma unroll
  for (int i = 0; i < 3; ++i) {
    const int idx = tid + 128 * i;  // 0..383 over 16x24
    const int r = idx / TCOLS;
    const int c = idx - r * TCOLS;
    int gy = py0 - PADK + r;
    gy = gy < 0 ? -gy : (gy >= HH ? 2 * HH - 2 - gy : gy);
    int gx = px0 - PADK + c;
    gx = gx < 0 ? -gx : (gx >= WW ? 2 * WW - 2 - gx : gx);
    __builtin_memcpy(&tr_[i][0], unet + ((size_t)gy * WW + gx) * 3, 12);
  }
  SBAR;
  wdma(0, 0);
  wdma(1, 1);
  SBAR;
#pragma unroll
  for (int i = 0; i < 3; ++i) {  // compiler waits the 3 tile loads (vmcnt(12))
    const int idx = tid + 128 * i;
    const int r = idx / TCOLS;
    const int c = idx - r * TCOLS;
    tile[r][c] = make_float4(tr_[i][0], tr_[i][1], tr_[i][2], 0.0f);
  }
  SBAR;
  asm volatile("s_waitcnt lgkmcnt(0)" ::: "memory");
  __builtin_amdgcn_s_barrier();  // publish tile; chunk DMAs stay in flight
  SBAR;

  const int wb0 = q * NW + 20 * jj;  // float offset of this thread's taps

  // ---- ph0: C0 ready when outstanding <= C1(6). ----
  asm volatile("s_waitcnt vmcnt(6)" ::: "memory");
  SBAR;
  do_phase(&wlds[0][wb0], 0 + wv, py0 + 0 + wv);
  SBAR;
  wdma(2, 0);  // buf0 reuse: only this wave's own half -> no barrier needed
  SBAR;
  // ---- ph1: C1 ready when <= S0(1)+C2(6)=7. ----
  asm volatile("s_waitcnt vmcnt(7)" ::: "memory");
  SBAR;
  do_phase(&wlds[1][wb0], 2 + wv, py0 + 2 + wv);
  SBAR;
  wdma(3, 1);
  SBAR;
  // ---- ph2: C2 ready when <= S1(1)+C3(6)=7. ----
  asm volatile("s_waitcnt vmcnt(7)" ::: "memory");
  SBAR;
  do_phase(&wlds[0][wb0], 4 + wv, py0 + 4 + wv);
  SBAR;
  // ---- ph3: C3 ready when <= S2(1). ----
  asm volatile("s_waitcnt vmcnt(1)" ::: "memory");
  SBAR;
  do_phase(&wlds[1][wb0], 6 + wv, py0 + 6 + wv);
}

extern "C" void kernel_launch(void* const* d_in, const int* in_sizes, int n_in,
                              void* d_out, int out_size, void* d_ws, size_t ws_size,
                              hipStream_t stream) {
  const float* unet = (const float*)d_in[0];  // [1024,1024,3] f32
  const float* cnn = (const float*)d_in[1];   // [1024,1024,81] f32
  float* out = (float*)d_out;                 // [1024,1024,3] f32
  dim3 grid(WW / TSX, HH / TSY);              // 64 x 128 = 8192 blocks
  dim3 block(128);
  denoiser_kpn<<<grid, block, 0, stream>>>(unet, cnn, out);
}